// Round 5
// baseline (3741.726 us; speedup 1.0000x reference)
//
#include <hip/hip_runtime.h>
#include <hip/hip_bf16.h>
#include <stdint.h>

using u16 = unsigned short;
using u32 = unsigned int;
typedef __bf16 bf16x8 __attribute__((ext_vector_type(8)));
typedef float f32x4 __attribute__((ext_vector_type(4)));

__device__ __forceinline__ void gld16(const void* g, void* lds) {
  __builtin_amdgcn_global_load_lds((const __attribute__((address_space(1))) void*)g,
                                   (__attribute__((address_space(3))) void*)lds,
                                   16, 0, 0);
}

__device__ __forceinline__ u16 f2bf(float f) {
  __hip_bfloat16 h = __float2bfloat16(f);
  return __builtin_bit_cast(u16, h);
}
__device__ __forceinline__ float bf2f(u16 b) {
  u32 u = ((u32)b) << 16;
  return __builtin_bit_cast(float, u);
}

// ---------------- fp32 -> bf16 convert ----------------
__global__ __launch_bounds__(256) void k_cvt(const float* __restrict__ in,
                                             u16* __restrict__ out, int n) {
  int i = (blockIdx.x * 256 + threadIdx.x) * 8;
  if (i >= n) return;
  float4 a = *(const float4*)(in + i);
  float4 b = *(const float4*)(in + i + 4);
  union { u16 h[8]; int4 v; } r;
  r.h[0] = f2bf(a.x); r.h[1] = f2bf(a.y); r.h[2] = f2bf(a.z); r.h[3] = f2bf(a.w);
  r.h[4] = f2bf(b.x); r.h[5] = f2bf(b.y); r.h[6] = f2bf(b.z); r.h[7] = f2bf(b.w);
  *(int4*)(out + i) = r.v;
}

// ---------------- fp32 -> split bf16 (hi + lo) convert ----------------
__global__ __launch_bounds__(256) void k_cvt2(const float* __restrict__ in,
                                              u16* __restrict__ outh,
                                              u16* __restrict__ outl, int n) {
  int i = (blockIdx.x * 256 + threadIdx.x) * 8;
  if (i >= n) return;
  union { u16 h[8]; int4 v; } rh, rl;
#pragma unroll
  for (int e = 0; e < 8; ++e) {
    float v = in[i + e];
    u16 hi = f2bf(v);
    rh.h[e] = hi;
    rl.h[e] = f2bf(v - bf2f(hi));
  }
  *(int4*)(outh + i) = rh.v;
  *(int4*)(outl + i) = rl.v;
}

// ---------------- 128x128 bf16 GEMM, C = A(MxK) * B(NxK)^T ----------------
template <bool RELU, typename OutT>
__global__ __launch_bounds__(256) void k_gemm(const u16* __restrict__ A,
                                              const u16* __restrict__ Bw,
                                              OutT* __restrict__ C,
                                              int M, int N, int K) {
  __shared__ __align__(16) char As[16384];
  __shared__ __align__(16) char Bs[16384];
  const int tid = threadIdx.x;
  const int w = tid >> 6, l = tid & 63;
  const int lr = l & 15, lg = l >> 4;
  const int wr = (w >> 1) * 64, wc = (w & 1) * 64;
  const int bm = blockIdx.y * 128, bn = blockIdx.x * 128;
  f32x4 acc[4][4] = {};
  for (int kt = 0; kt < K; kt += 64) {
    __syncthreads();
#pragma unroll
    for (int i = 0; i < 4; ++i) {
      int p = i * 4096 + w * 1024 + l * 16;
      int row = p >> 7;                       // 128B per row (64 bf16)
      int kbl = (p & 127) ^ ((row & 7) << 4); // inverse-swizzled source
      gld16((const char*)(A + (size_t)(bm + row) * K + kt) + kbl, As + i * 4096 + w * 1024);
      gld16((const char*)(Bw + (size_t)(bn + row) * K + kt) + kbl, Bs + i * 4096 + w * 1024);
    }
    __syncthreads();
#pragma unroll
    for (int kk = 0; kk < 64; kk += 32) {
      bf16x8 af[4], bfr[4];
#pragma unroll
      for (int m = 0; m < 4; ++m) {
        int r = wr + m * 16 + lr;
        af[m] = *(const bf16x8*)(As + r * 128 + (((kk + lg * 8) * 2) ^ ((r & 7) << 4)));
      }
#pragma unroll
      for (int n = 0; n < 4; ++n) {
        int r = wc + n * 16 + lr;
        bfr[n] = *(const bf16x8*)(Bs + r * 128 + (((kk + lg * 8) * 2) ^ ((r & 7) << 4)));
      }
#pragma unroll
      for (int m = 0; m < 4; ++m)
#pragma unroll
        for (int n = 0; n < 4; ++n)
          acc[m][n] = __builtin_amdgcn_mfma_f32_16x16x32_bf16(af[m], bfr[n], acc[m][n], 0, 0, 0);
    }
  }
#pragma unroll
  for (int m = 0; m < 4; ++m)
#pragma unroll
    for (int n = 0; n < 4; ++n)
#pragma unroll
      for (int j = 0; j < 4; ++j) {
        int row = bm + wr + m * 16 + lg * 4 + j;   // D: row=(lane>>4)*4+reg
        int col = bn + wc + n * 16 + lr;           // D: col=lane&15
        float v = acc[m][n][j];
        if (RELU) v = fmaxf(v, 0.f);
        if constexpr (sizeof(OutT) == 2)
          ((u16*)C)[(size_t)row * N + col] = f2bf(v);
        else
          ((float*)C)[(size_t)row * N + col] = v;
      }
}

// ------- split-precision GEMM: C = (Ah+Al)(Bh+Bl)^T (drop Al*Bl), fp32 out -------
template <bool RELU>
__global__ __launch_bounds__(256) void k_gemm3(const u16* __restrict__ Ah_,
                                               const u16* __restrict__ Al_,
                                               const u16* __restrict__ Bh_,
                                               const u16* __restrict__ Bl_,
                                               float* __restrict__ C,
                                               int M, int N, int K) {
  __shared__ __align__(16) char Ahs[16384];
  __shared__ __align__(16) char Als[16384];
  __shared__ __align__(16) char Bhs[16384];
  __shared__ __align__(16) char Bls[16384];
  const int tid = threadIdx.x;
  const int w = tid >> 6, l = tid & 63;
  const int lr = l & 15, lg = l >> 4;
  const int wr = (w >> 1) * 64, wc = (w & 1) * 64;
  const int bm = blockIdx.y * 128, bn = blockIdx.x * 128;
  f32x4 acc[4][4] = {};
  for (int kt = 0; kt < K; kt += 64) {
    __syncthreads();
#pragma unroll
    for (int i = 0; i < 4; ++i) {
      int p = i * 4096 + w * 1024 + l * 16;
      int row = p >> 7;
      int kbl = (p & 127) ^ ((row & 7) << 4);
      size_t goa = (size_t)(bm + row) * K + kt;
      size_t gob = (size_t)(bn + row) * K + kt;
      gld16((const char*)(Ah_ + goa) + kbl, Ahs + i * 4096 + w * 1024);
      gld16((const char*)(Al_ + goa) + kbl, Als + i * 4096 + w * 1024);
      gld16((const char*)(Bh_ + gob) + kbl, Bhs + i * 4096 + w * 1024);
      gld16((const char*)(Bl_ + gob) + kbl, Bls + i * 4096 + w * 1024);
    }
    __syncthreads();
#pragma unroll
    for (int kk = 0; kk < 64; kk += 32) {
      bf16x8 ah[4], al[4], bh[4], bl[4];
#pragma unroll
      for (int m = 0; m < 4; ++m) {
        int r = wr + m * 16 + lr;
        int off = r * 128 + (((kk + lg * 8) * 2) ^ ((r & 7) << 4));
        ah[m] = *(const bf16x8*)(Ahs + off);
        al[m] = *(const bf16x8*)(Als + off);
      }
#pragma unroll
      for (int n = 0; n < 4; ++n) {
        int r = wc + n * 16 + lr;
        int off = r * 128 + (((kk + lg * 8) * 2) ^ ((r & 7) << 4));
        bh[n] = *(const bf16x8*)(Bhs + off);
        bl[n] = *(const bf16x8*)(Bls + off);
      }
#pragma unroll
      for (int m = 0; m < 4; ++m)
#pragma unroll
        for (int n = 0; n < 4; ++n) {
          acc[m][n] = __builtin_amdgcn_mfma_f32_16x16x32_bf16(ah[m], bh[n], acc[m][n], 0, 0, 0);
          acc[m][n] = __builtin_amdgcn_mfma_f32_16x16x32_bf16(ah[m], bl[n], acc[m][n], 0, 0, 0);
          acc[m][n] = __builtin_amdgcn_mfma_f32_16x16x32_bf16(al[m], bh[n], acc[m][n], 0, 0, 0);
        }
    }
  }
#pragma unroll
  for (int m = 0; m < 4; ++m)
#pragma unroll
    for (int n = 0; n < 4; ++n)
#pragma unroll
      for (int j = 0; j < 4; ++j) {
        int row = bm + wr + m * 16 + lg * 4 + j;
        int col = bn + wc + n * 16 + lr;
        float v = acc[m][n][j];
        if (RELU) v = fmaxf(v, 0.f);
        C[(size_t)row * N + col] = v;
      }
}

// ---------------- naive attention, step 1: S = scale * Q K^T ----------------
// grid (8, 8, 8) = (bn, bm, h); per-batch launch. lda=ldb=3072, K=128.
__global__ __launch_bounds__(256) void k_qkt(const u16* __restrict__ qkv,
                                             float* __restrict__ S, int b) {
  __shared__ __align__(16) char As[16384];
  __shared__ __align__(16) char Bs[16384];
  const int tid = threadIdx.x;
  const int w = tid >> 6, l = tid & 63;
  const int lr = l & 15, lg = l >> 4;
  const int wr = (w >> 1) * 64, wc = (w & 1) * 64;
  const int bm = blockIdx.y * 128, bn = blockIdx.x * 128;
  const int h = blockIdx.z;
  const u16* Aq = qkv + (size_t)b * 1024 * 3072 + h * 128;          // Q rows
  const u16* Bk = qkv + (size_t)b * 1024 * 3072 + 1024 + h * 128;   // K rows
  f32x4 acc[4][4] = {};
  for (int kt = 0; kt < 128; kt += 64) {
    __syncthreads();
#pragma unroll
    for (int i = 0; i < 4; ++i) {
      int p = i * 4096 + w * 1024 + l * 16;
      int row = p >> 7;
      int kbl = (p & 127) ^ ((row & 7) << 4);
      gld16((const char*)(Aq + (size_t)(bm + row) * 3072 + kt) + kbl, As + i * 4096 + w * 1024);
      gld16((const char*)(Bk + (size_t)(bn + row) * 3072 + kt) + kbl, Bs + i * 4096 + w * 1024);
    }
    __syncthreads();
#pragma unroll
    for (int kk = 0; kk < 64; kk += 32) {
      bf16x8 af[4], bfr[4];
#pragma unroll
      for (int m = 0; m < 4; ++m) {
        int r = wr + m * 16 + lr;
        af[m] = *(const bf16x8*)(As + r * 128 + (((kk + lg * 8) * 2) ^ ((r & 7) << 4)));
      }
#pragma unroll
      for (int n = 0; n < 4; ++n) {
        int r = wc + n * 16 + lr;
        bfr[n] = *(const bf16x8*)(Bs + r * 128 + (((kk + lg * 8) * 2) ^ ((r & 7) << 4)));
      }
#pragma unroll
      for (int m = 0; m < 4; ++m)
#pragma unroll
        for (int n = 0; n < 4; ++n)
          acc[m][n] = __builtin_amdgcn_mfma_f32_16x16x32_bf16(af[m], bfr[n], acc[m][n], 0, 0, 0);
    }
  }
  const float scale = 0.08838834764831845f;  // 1/sqrt(128)
#pragma unroll
  for (int m = 0; m < 4; ++m)
#pragma unroll
    for (int n = 0; n < 4; ++n)
#pragma unroll
      for (int j = 0; j < 4; ++j) {
        int row = bm + wr + m * 16 + lg * 4 + j;
        int col = bn + wc + n * 16 + lr;
        S[((size_t)h << 20) + (size_t)row * 1024 + col] = acc[m][n][j] * scale;
      }
}

// ---------------- naive attention, step 2: row softmax (fp32, in place) ----------------
__global__ __launch_bounds__(256) void k_softmax(float* __restrict__ S) {
  const int row = blockIdx.x, h = blockIdx.y, tid = threadIdx.x;
  const int wv = tid >> 6, l = tid & 63;
  float* p = S + ((size_t)h << 20) + (size_t)row * 1024;
  float4 v = *(const float4*)(p + tid * 4);
  float mx = fmaxf(fmaxf(v.x, v.y), fmaxf(v.z, v.w));
#pragma unroll
  for (int m = 1; m < 64; m <<= 1) mx = fmaxf(mx, __shfl_xor(mx, m));
  __shared__ float rm[4], rsum[4];
  if (l == 0) rm[wv] = mx;
  __syncthreads();
  mx = fmaxf(fmaxf(rm[0], rm[1]), fmaxf(rm[2], rm[3]));
  float e0 = __expf(v.x - mx), e1 = __expf(v.y - mx);
  float e2 = __expf(v.z - mx), e3 = __expf(v.w - mx);
  float s = e0 + e1 + e2 + e3;
#pragma unroll
  for (int m = 1; m < 64; m <<= 1) s += __shfl_xor(s, m);
  if (l == 0) rsum[wv] = s;
  __syncthreads();
  s = rsum[0] + rsum[1] + rsum[2] + rsum[3];
  float inv = 1.f / s;
  *(float4*)(p + tid * 4) = make_float4(e0 * inv, e1 * inv, e2 * inv, e3 * inv);
}

// ---------------- naive attention, step 3: ctx = P V ----------------
// grid (1024, 8) per batch; block = 128 threads, one per d.
__global__ __launch_bounds__(128) void k_pv(const u16* __restrict__ qkv,
                                            const float* __restrict__ S,
                                            u16* __restrict__ ctx, int b) {
  __shared__ float Pr[1024];
  const int q = blockIdx.x, h = blockIdx.y, d = threadIdx.x;
  const float* p = S + ((size_t)h << 20) + (size_t)q * 1024;
#pragma unroll
  for (int i = 0; i < 8; ++i) Pr[i * 128 + d] = p[i * 128 + d];
  __syncthreads();
  const u16* vbase = qkv + (size_t)b * 1024 * 3072 + 2048 + h * 128 + d;
  float acc = 0.f;
#pragma unroll 8
  for (int k = 0; k < 1024; ++k)
    acc += Pr[k] * bf2f(vbase[(size_t)k * 3072]);
  ctx[((size_t)b * 1024 + q) * 1024 + h * 128 + d] = f2bf(acc);
}

// ---------------- LayerNorm(residual + attn_out) -> split h ----------------
__global__ __launch_bounds__(256) void k_ln2(const u16* __restrict__ ao,
                                             const float* __restrict__ x,
                                             u16* __restrict__ hh,
                                             u16* __restrict__ hl) {
  const int row = blockIdx.x, tid = threadIdx.x;
  const int w = tid >> 6, l = tid & 63;
  size_t base = (size_t)row * 1024 + tid * 4;
  union { u16 hh4[4]; int2 v; } aa;
  aa.v = *(const int2*)(ao + base);
  float4 xf = *(const float4*)(x + base);
  float v0 = bf2f(aa.hh4[0]) + xf.x;
  float v1 = bf2f(aa.hh4[1]) + xf.y;
  float v2 = bf2f(aa.hh4[2]) + xf.z;
  float v3 = bf2f(aa.hh4[3]) + xf.w;
  float s = v0 + v1 + v2 + v3;
  float s2 = v0 * v0 + v1 * v1 + v2 * v2 + v3 * v3;
#pragma unroll
  for (int m = 1; m < 64; m <<= 1) {
    s += __shfl_xor(s, m);
    s2 += __shfl_xor(s2, m);
  }
  __shared__ float rs[4], rq[4];
  if (l == 0) { rs[w] = s; rq[w] = s2; }
  __syncthreads();
  s = rs[0] + rs[1] + rs[2] + rs[3];
  s2 = rq[0] + rq[1] + rq[2] + rq[3];
  float mu = s * (1.f / 1024.f);
  float var = s2 * (1.f / 1024.f) - mu * mu;
  float rstd = rsqrtf(var + 1e-5f);
  float r0 = (v0 - mu) * rstd, r1 = (v1 - mu) * rstd;
  float r2 = (v2 - mu) * rstd, r3 = (v3 - mu) * rstd;
  union { u16 q[4]; int2 v; } oh, ol;
  oh.q[0] = f2bf(r0); ol.q[0] = f2bf(r0 - bf2f(oh.q[0]));
  oh.q[1] = f2bf(r1); ol.q[1] = f2bf(r1 - bf2f(oh.q[1]));
  oh.q[2] = f2bf(r2); ol.q[2] = f2bf(r2 - bf2f(oh.q[2]));
  oh.q[3] = f2bf(r3); ol.q[3] = f2bf(r3 - bf2f(oh.q[3]));
  *(int2*)(hh + base) = oh.v;
  *(int2*)(hl + base) = ol.v;
}

// ---------------- fused enc2 + dec1 (relu), all fp32 ----------------
__global__ __launch_bounds__(256) void k_mid2(const float* __restrict__ e1,
                                              const float* __restrict__ we2,
                                              const float* __restrict__ wd1,
                                              float* __restrict__ enc_out,
                                              u16* __restrict__ d1h,
                                              u16* __restrict__ d1l) {
  __shared__ float W2f[64 * 129];
  __shared__ float W1f[128 * 65];
  __shared__ float E1f[16 * 128];
  __shared__ float ENf[16 * 64];
  const int tid = threadIdx.x;
  const int r0 = blockIdx.x * 16;
#pragma unroll
  for (int i = 0; i < 32; ++i) {
    int idx = i * 256 + tid;
    W2f[(idx >> 7) * 129 + (idx & 127)] = we2[idx];
    W1f[(idx >> 6) * 65 + (idx & 63)] = wd1[idx];
  }
#pragma unroll
  for (int i = 0; i < 8; ++i) {
    int idx = i * 256 + tid;
    E1f[idx] = e1[(size_t)r0 * 128 + idx];
  }
  __syncthreads();
#pragma unroll
  for (int o = 0; o < 4; ++o) {
    int idx = o * 256 + tid;
    int r = idx >> 6, cc = idx & 63;
    float acc = 0.f;
#pragma unroll 8
    for (int c = 0; c < 128; ++c) acc += E1f[r * 128 + c] * W2f[cc * 129 + c];
    acc = fmaxf(acc, 0.f);
    ENf[r * 64 + cc] = acc;
    enc_out[(size_t)(r0 + r) * 64 + cc] = acc;
  }
  __syncthreads();
#pragma unroll
  for (int o = 0; o < 8; ++o) {
    int idx = o * 256 + tid;
    int r = idx >> 7, cc = idx & 127;
    float acc = 0.f;
#pragma unroll 8
    for (int c = 0; c < 64; ++c) acc += ENf[r * 64 + c] * W1f[cc * 65 + c];
    acc = fmaxf(acc, 0.f);
    u16 hi = f2bf(acc);
    d1h[(size_t)(r0 + r) * 128 + cc] = hi;
    d1l[(size_t)(r0 + r) * 128 + cc] = f2bf(acc - bf2f(hi));
  }
}

// ---------------- launch ----------------
extern "C" void kernel_launch(void* const* d_in, const int* in_sizes, int n_in,
                              void* d_out, int out_size, void* d_ws, size_t ws_size,
                              hipStream_t stream) {
  const float* x     = (const float*)d_in[0];
  const float* w_in  = (const float*)d_in[1];
  const float* w_out = (const float*)d_in[2];
  const float* w_e1  = (const float*)d_in[3];
  const float* w_e2  = (const float*)d_in[4];
  const float* w_d1  = (const float*)d_in[5];
  const float* w_d2  = (const float*)d_in[6];

  char* ws = (char*)d_ws;
  u16* qkvb  = (u16*)(ws + 0);           // 100,663,296  [until attn done]
  u16* hbh   = (u16*)(ws + 0);           // 33,554,432   [after attn]
  u16* hbl   = (u16*)(ws + 33554432);    // 33,554,432
  float* e1b = (float*)(ws + 67108864);  // 8,388,608 (fp32)
  u16* d1oh  = (u16*)(ws + 75497472);    // 4,194,304
  u16* d1ol  = (u16*)(ws + 79691776);    // 4,194,304
  float* Sb  = (float*)(ws + 100663296); // 33,554,432 (8 heads x 1024 x 1024 fp32)
  u16* xb    = (u16*)(ws + 134217728);   // 33,554,432   [until qkv gemm]
  u16* ctxb  = (u16*)(ws + 134217728);   // reuses xb
  u16* aob   = (u16*)(ws + 167772160);   // 33,554,432
  u16* wbin  = (u16*)(ws + 201326592);   // 6,291,456
  u16* wbout = (u16*)(ws + 207618048);   // 2,097,152
  u16* wbe1h = (u16*)(ws + 209715200);   // 262,144
  u16* wbe1l = (u16*)(ws + 209977344);   // 262,144
  u16* wbd2h = (u16*)(ws + 210239488);   // 262,144
  u16* wbd2l = (u16*)(ws + 210501632);   // 262,144

  float* recon = (float*)d_out;
  float* enc_out = (float*)d_out + 16777216;

  k_cvt<<<8192, 256, 0, stream>>>(x, xb, 16777216);
  k_cvt<<<1536, 256, 0, stream>>>(w_in, wbin, 3145728);
  k_cvt<<<512, 256, 0, stream>>>(w_out, wbout, 1048576);
  k_cvt2<<<64, 256, 0, stream>>>(w_e1, wbe1h, wbe1l, 131072);
  k_cvt2<<<64, 256, 0, stream>>>(w_d2, wbd2h, wbd2l, 131072);

  k_gemm<false, u16><<<dim3(24, 128), 256, 0, stream>>>(xb, wbin, qkvb, 16384, 3072, 1024);

  for (int b = 0; b < 16; ++b) {
    k_qkt<<<dim3(8, 8, 8), 256, 0, stream>>>(qkvb, Sb, b);
    k_softmax<<<dim3(1024, 8), 256, 0, stream>>>(Sb);
    k_pv<<<dim3(1024, 8), 128, 0, stream>>>(qkvb, Sb, ctxb, b);
  }

  k_gemm<false, u16><<<dim3(8, 128), 256, 0, stream>>>(ctxb, wbout, aob, 16384, 1024, 1024);
  k_ln2<<<16384, 256, 0, stream>>>(aob, x, hbh, hbl);
  k_gemm3<true><<<dim3(1, 128), 256, 0, stream>>>(hbh, hbl, wbe1h, wbe1l, e1b, 16384, 128, 1024);
  k_mid2<<<1024, 256, 0, stream>>>(e1b, w_e2, w_d1, enc_out, d1oh, d1ol);
  k_gemm3<false><<<dim3(8, 128), 256, 0, stream>>>(d1oh, d1ol, wbd2h, wbd2l, recon, 16384, 1024, 128);
}

// Round 8
// 2132.988 us; speedup vs baseline: 1.7542x; 1.7542x over previous
//
#include <hip/hip_runtime.h>
#include <hip/hip_bf16.h>
#include <stdint.h>

using u16 = unsigned short;
using u32 = unsigned int;
typedef __bf16 bf16x8 __attribute__((ext_vector_type(8)));
typedef float f32x4 __attribute__((ext_vector_type(4)));

__device__ __forceinline__ void gld16(const void* g, void* lds) {
  __builtin_amdgcn_global_load_lds((const __attribute__((address_space(1))) void*)g,
                                   (__attribute__((address_space(3))) void*)lds,
                                   16, 0, 0);
}

__device__ __forceinline__ u16 f2bf(float f) {
  __hip_bfloat16 h = __float2bfloat16(f);
  return __builtin_bit_cast(u16, h);
}
__device__ __forceinline__ float bf2f(u16 b) {
  u32 u = ((u32)b) << 16;
  return __builtin_bit_cast(float, u);
}

// ---------------- fp32 -> bf16 convert ----------------
__global__ __launch_bounds__(256) void k_cvt(const float* __restrict__ in,
                                             u16* __restrict__ out, int n) {
  int i = (blockIdx.x * 256 + threadIdx.x) * 8;
  if (i >= n) return;
  float4 a = *(const float4*)(in + i);
  float4 b = *(const float4*)(in + i + 4);
  union { u16 h[8]; int4 v; } r;
  r.h[0] = f2bf(a.x); r.h[1] = f2bf(a.y); r.h[2] = f2bf(a.z); r.h[3] = f2bf(a.w);
  r.h[4] = f2bf(b.x); r.h[5] = f2bf(b.y); r.h[6] = f2bf(b.z); r.h[7] = f2bf(b.w);
  *(int4*)(out + i) = r.v;
}

// ---------------- fp32 -> split bf16 (hi + lo) convert ----------------
__global__ __launch_bounds__(256) void k_cvt2(const float* __restrict__ in,
                                              u16* __restrict__ outh,
                                              u16* __restrict__ outl, int n) {
  int i = (blockIdx.x * 256 + threadIdx.x) * 8;
  if (i >= n) return;
  union { u16 h[8]; int4 v; } rh, rl;
#pragma unroll
  for (int e = 0; e < 8; ++e) {
    float v = in[i + e];
    u16 hi = f2bf(v);
    rh.h[e] = hi;
    rl.h[e] = f2bf(v - bf2f(hi));
  }
  *(int4*)(outh + i) = rh.v;
  *(int4*)(outl + i) = rl.v;
}

// ---------------- 128x128 bf16 GEMM, C = A(MxK) * B(NxK)^T ----------------
template <bool RELU, typename OutT>
__global__ __launch_bounds__(256) void k_gemm(const u16* __restrict__ A,
                                              const u16* __restrict__ Bw,
                                              OutT* __restrict__ C,
                                              int M, int N, int K) {
  __shared__ __align__(16) char As[16384];
  __shared__ __align__(16) char Bs[16384];
  const int tid = threadIdx.x;
  const int w = tid >> 6, l = tid & 63;
  const int lr = l & 15, lg = l >> 4;
  const int wr = (w >> 1) * 64, wc = (w & 1) * 64;
  const int bm = blockIdx.y * 128, bn = blockIdx.x * 128;
  f32x4 acc[4][4] = {};
  for (int kt = 0; kt < K; kt += 64) {
    __syncthreads();
#pragma unroll
    for (int i = 0; i < 4; ++i) {
      int p = i * 4096 + w * 1024 + l * 16;
      int row = p >> 7;                       // 128B per row (64 bf16)
      int kbl = (p & 127) ^ ((row & 7) << 4); // inverse-swizzled source
      gld16((const char*)(A + (size_t)(bm + row) * K + kt) + kbl, As + i * 4096 + w * 1024);
      gld16((const char*)(Bw + (size_t)(bn + row) * K + kt) + kbl, Bs + i * 4096 + w * 1024);
    }
    __syncthreads();
#pragma unroll
    for (int kk = 0; kk < 64; kk += 32) {
      bf16x8 af[4], bfr[4];
#pragma unroll
      for (int m = 0; m < 4; ++m) {
        int r = wr + m * 16 + lr;
        af[m] = *(const bf16x8*)(As + r * 128 + (((kk + lg * 8) * 2) ^ ((r & 7) << 4)));
      }
#pragma unroll
      for (int n = 0; n < 4; ++n) {
        int r = wc + n * 16 + lr;
        bfr[n] = *(const bf16x8*)(Bs + r * 128 + (((kk + lg * 8) * 2) ^ ((r & 7) << 4)));
      }
#pragma unroll
      for (int m = 0; m < 4; ++m)
#pragma unroll
        for (int n = 0; n < 4; ++n)
          acc[m][n] = __builtin_amdgcn_mfma_f32_16x16x32_bf16(af[m], bfr[n], acc[m][n], 0, 0, 0);
    }
  }
#pragma unroll
  for (int m = 0; m < 4; ++m)
#pragma unroll
    for (int n = 0; n < 4; ++n)
#pragma unroll
      for (int j = 0; j < 4; ++j) {
        int row = bm + wr + m * 16 + lg * 4 + j;   // D: row=(lane>>4)*4+reg
        int col = bn + wc + n * 16 + lr;           // D: col=lane&15
        float v = acc[m][n][j];
        if (RELU) v = fmaxf(v, 0.f);
        if constexpr (sizeof(OutT) == 2)
          ((u16*)C)[(size_t)row * N + col] = f2bf(v);
        else
          ((float*)C)[(size_t)row * N + col] = v;
      }
}

// ------- split-precision GEMM: C = (Ah+Al)(Bh+Bl)^T (drop Al*Bl), fp32 out -------
template <bool RELU>
__global__ __launch_bounds__(256) void k_gemm3(const u16* __restrict__ Ah_,
                                               const u16* __restrict__ Al_,
                                               const u16* __restrict__ Bh_,
                                               const u16* __restrict__ Bl_,
                                               float* __restrict__ C,
                                               int M, int N, int K) {
  __shared__ __align__(16) char Ahs[16384];
  __shared__ __align__(16) char Als[16384];
  __shared__ __align__(16) char Bhs[16384];
  __shared__ __align__(16) char Bls[16384];
  const int tid = threadIdx.x;
  const int w = tid >> 6, l = tid & 63;
  const int lr = l & 15, lg = l >> 4;
  const int wr = (w >> 1) * 64, wc = (w & 1) * 64;
  const int bm = blockIdx.y * 128, bn = blockIdx.x * 128;
  f32x4 acc[4][4] = {};
  for (int kt = 0; kt < K; kt += 64) {
    __syncthreads();
#pragma unroll
    for (int i = 0; i < 4; ++i) {
      int p = i * 4096 + w * 1024 + l * 16;
      int row = p >> 7;
      int kbl = (p & 127) ^ ((row & 7) << 4);
      size_t goa = (size_t)(bm + row) * K + kt;
      size_t gob = (size_t)(bn + row) * K + kt;
      gld16((const char*)(Ah_ + goa) + kbl, Ahs + i * 4096 + w * 1024);
      gld16((const char*)(Al_ + goa) + kbl, Als + i * 4096 + w * 1024);
      gld16((const char*)(Bh_ + gob) + kbl, Bhs + i * 4096 + w * 1024);
      gld16((const char*)(Bl_ + gob) + kbl, Bls + i * 4096 + w * 1024);
    }
    __syncthreads();
#pragma unroll
    for (int kk = 0; kk < 64; kk += 32) {
      bf16x8 ah[4], al[4], bh[4], bl[4];
#pragma unroll
      for (int m = 0; m < 4; ++m) {
        int r = wr + m * 16 + lr;
        int off = r * 128 + (((kk + lg * 8) * 2) ^ ((r & 7) << 4));
        ah[m] = *(const bf16x8*)(Ahs + off);
        al[m] = *(const bf16x8*)(Als + off);
      }
#pragma unroll
      for (int n = 0; n < 4; ++n) {
        int r = wc + n * 16 + lr;
        int off = r * 128 + (((kk + lg * 8) * 2) ^ ((r & 7) << 4));
        bh[n] = *(const bf16x8*)(Bhs + off);
        bl[n] = *(const bf16x8*)(Bls + off);
      }
#pragma unroll
      for (int m = 0; m < 4; ++m)
#pragma unroll
        for (int n = 0; n < 4; ++n) {
          acc[m][n] = __builtin_amdgcn_mfma_f32_16x16x32_bf16(ah[m], bh[n], acc[m][n], 0, 0, 0);
          acc[m][n] = __builtin_amdgcn_mfma_f32_16x16x32_bf16(ah[m], bl[n], acc[m][n], 0, 0, 0);
          acc[m][n] = __builtin_amdgcn_mfma_f32_16x16x32_bf16(al[m], bh[n], acc[m][n], 0, 0, 0);
        }
    }
  }
#pragma unroll
  for (int m = 0; m < 4; ++m)
#pragma unroll
    for (int n = 0; n < 4; ++n)
#pragma unroll
      for (int j = 0; j < 4; ++j) {
        int row = bm + wr + m * 16 + lg * 4 + j;
        int col = bn + wc + n * 16 + lr;
        float v = acc[m][n][j];
        if (RELU) v = fmaxf(v, 0.f);
        C[(size_t)row * N + col] = v;
      }
}

// ---------------- naive attention, step 1: S = scale * Q K^T ----------------
// grid (8, 8, 8) = (bn, bm, h); per-batch launch. lda=ldb=3072, K=128.
__global__ __launch_bounds__(256) void k_qkt(const u16* __restrict__ qkv,
                                             float* __restrict__ S, int b) {
  __shared__ __align__(16) char As[16384];
  __shared__ __align__(16) char Bs[16384];
  const int tid = threadIdx.x;
  const int w = tid >> 6, l = tid & 63;
  const int lr = l & 15, lg = l >> 4;
  const int wr = (w >> 1) * 64, wc = (w & 1) * 64;
  const int bm = blockIdx.y * 128, bn = blockIdx.x * 128;
  const int h = blockIdx.z;
  const u16* Aq = qkv + (size_t)b * 1024 * 3072 + h * 128;          // Q rows
  const u16* Bk = qkv + (size_t)b * 1024 * 3072 + 1024 + h * 128;   // K rows
  f32x4 acc[4][4] = {};
  for (int kt = 0; kt < 128; kt += 64) {
    __syncthreads();
#pragma unroll
    for (int i = 0; i < 4; ++i) {
      int p = i * 4096 + w * 1024 + l * 16;
      int row = p >> 7;
      int kbl = (p & 127) ^ ((row & 7) << 4);
      gld16((const char*)(Aq + (size_t)(bm + row) * 3072 + kt) + kbl, As + i * 4096 + w * 1024);
      gld16((const char*)(Bk + (size_t)(bn + row) * 3072 + kt) + kbl, Bs + i * 4096 + w * 1024);
    }
    __syncthreads();
#pragma unroll
    for (int kk = 0; kk < 64; kk += 32) {
      bf16x8 af[4], bfr[4];
#pragma unroll
      for (int m = 0; m < 4; ++m) {
        int r = wr + m * 16 + lr;
        af[m] = *(const bf16x8*)(As + r * 128 + (((kk + lg * 8) * 2) ^ ((r & 7) << 4)));
      }
#pragma unroll
      for (int n = 0; n < 4; ++n) {
        int r = wc + n * 16 + lr;
        bfr[n] = *(const bf16x8*)(Bs + r * 128 + (((kk + lg * 8) * 2) ^ ((r & 7) << 4)));
      }
#pragma unroll
      for (int m = 0; m < 4; ++m)
#pragma unroll
        for (int n = 0; n < 4; ++n)
          acc[m][n] = __builtin_amdgcn_mfma_f32_16x16x32_bf16(af[m], bfr[n], acc[m][n], 0, 0, 0);
    }
  }
  const float scale = 0.08838834764831845f;  // 1/sqrt(128)
#pragma unroll
  for (int m = 0; m < 4; ++m)
#pragma unroll
    for (int n = 0; n < 4; ++n)
#pragma unroll
      for (int j = 0; j < 4; ++j) {
        int row = bm + wr + m * 16 + lg * 4 + j;
        int col = bn + wc + n * 16 + lr;
        S[((size_t)h << 20) + (size_t)row * 1024 + col] = acc[m][n][j] * scale;
      }
}

// ---------------- naive attention, step 2: row softmax (fp32, in place) ----------------
__global__ __launch_bounds__(256) void k_softmax(float* __restrict__ S) {
  const int row = blockIdx.x, h = blockIdx.y, tid = threadIdx.x;
  const int wv = tid >> 6, l = tid & 63;
  float* p = S + ((size_t)h << 20) + (size_t)row * 1024;
  float4 v = *(const float4*)(p + tid * 4);
  float mx = fmaxf(fmaxf(v.x, v.y), fmaxf(v.z, v.w));
#pragma unroll
  for (int m = 1; m < 64; m <<= 1) mx = fmaxf(mx, __shfl_xor(mx, m));
  __shared__ float rm[4], rsum[4];
  if (l == 0) rm[wv] = mx;
  __syncthreads();
  mx = fmaxf(fmaxf(rm[0], rm[1]), fmaxf(rm[2], rm[3]));
  float e0 = __expf(v.x - mx), e1 = __expf(v.y - mx);
  float e2 = __expf(v.z - mx), e3 = __expf(v.w - mx);
  float s = e0 + e1 + e2 + e3;
#pragma unroll
  for (int m = 1; m < 64; m <<= 1) s += __shfl_xor(s, m);
  if (l == 0) rsum[wv] = s;
  __syncthreads();
  s = rsum[0] + rsum[1] + rsum[2] + rsum[3];
  float inv = 1.f / s;
  *(float4*)(p + tid * 4) = make_float4(e0 * inv, e1 * inv, e2 * inv, e3 * inv);
}

// ---------------- naive attention, step 3: ctx = P V (8 q-rows per block) ----
// Structurally identical to R5's k_pv (scalar coalesced V reads, float P in LDS,
// same per-thread k-ascending accumulation) — only the grid regroups so each
// V element read is reused across 8 q rows. grid (128, 8); block 128 (one/d).
__global__ __launch_bounds__(128) void k_pv8(const u16* __restrict__ qkv,
                                             const float* __restrict__ S,
                                             u16* __restrict__ ctx, int b) {
  __shared__ float Pr[8][1024];   // 32 KB
  const int q0 = blockIdx.x * 8, h = blockIdx.y, d = threadIdx.x;
  const float* ps = S + ((size_t)h << 20) + (size_t)q0 * 1024;
  float* Pf = &Pr[0][0];
#pragma unroll
  for (int i = 0; i < 64; ++i) Pf[i * 128 + d] = ps[i * 128 + d];
  __syncthreads();
  const u16* vbase = qkv + (size_t)b * 3145728 + 2048 + h * 128 + d;
  float acc[8] = {};
#pragma unroll 8
  for (int k = 0; k < 1024; ++k) {
    float v = bf2f(vbase[(size_t)k * 3072]);
#pragma unroll
    for (int q = 0; q < 8; ++q) acc[q] += Pr[q][k] * v;
  }
#pragma unroll
  for (int q = 0; q < 8; ++q)
    ctx[((size_t)b * 1024 + q0 + q) * 1024 + h * 128 + d] = f2bf(acc[q]);
}

// ---------------- LayerNorm(residual + attn_out) -> split h ----------------
__global__ __launch_bounds__(256) void k_ln2(const u16* __restrict__ ao,
                                             const float* __restrict__ x,
                                             u16* __restrict__ hh,
                                             u16* __restrict__ hl) {
  const int row = blockIdx.x, tid = threadIdx.x;
  const int w = tid >> 6, l = tid & 63;
  size_t base = (size_t)row * 1024 + tid * 4;
  union { u16 hh4[4]; int2 v; } aa;
  aa.v = *(const int2*)(ao + base);
  float4 xf = *(const float4*)(x + base);
  float v0 = bf2f(aa.hh4[0]) + xf.x;
  float v1 = bf2f(aa.hh4[1]) + xf.y;
  float v2 = bf2f(aa.hh4[2]) + xf.z;
  float v3 = bf2f(aa.hh4[3]) + xf.w;
  float s = v0 + v1 + v2 + v3;
  float s2 = v0 * v0 + v1 * v1 + v2 * v2 + v3 * v3;
#pragma unroll
  for (int m = 1; m < 64; m <<= 1) {
    s += __shfl_xor(s, m);
    s2 += __shfl_xor(s2, m);
  }
  __shared__ float rs[4], rq[4];
  if (l == 0) { rs[w] = s; rq[w] = s2; }
  __syncthreads();
  s = rs[0] + rs[1] + rs[2] + rs[3];
  s2 = rq[0] + rq[1] + rq[2] + rq[3];
  float mu = s * (1.f / 1024.f);
  float var = s2 * (1.f / 1024.f) - mu * mu;
  float rstd = rsqrtf(var + 1e-5f);
  float r0 = (v0 - mu) * rstd, r1 = (v1 - mu) * rstd;
  float r2 = (v2 - mu) * rstd, r3 = (v3 - mu) * rstd;
  union { u16 q[4]; int2 v; } oh, ol;
  oh.q[0] = f2bf(r0); ol.q[0] = f2bf(r0 - bf2f(oh.q[0]));
  oh.q[1] = f2bf(r1); ol.q[1] = f2bf(r1 - bf2f(oh.q[1]));
  oh.q[2] = f2bf(r2); ol.q[2] = f2bf(r2 - bf2f(oh.q[2]));
  oh.q[3] = f2bf(r3); ol.q[3] = f2bf(r3 - bf2f(oh.q[3]));
  *(int2*)(hh + base) = oh.v;
  *(int2*)(hl + base) = ol.v;
}

// ---------------- fused enc2 + dec1 (relu), all fp32 ----------------
__global__ __launch_bounds__(256) void k_mid2(const float* __restrict__ e1,
                                              const float* __restrict__ we2,
                                              const float* __restrict__ wd1,
                                              float* __restrict__ enc_out,
                                              u16* __restrict__ d1h,
                                              u16* __restrict__ d1l) {
  __shared__ float W2f[64 * 129];
  __shared__ float W1f[128 * 65];
  __shared__ float E1f[16 * 128];
  __shared__ float ENf[16 * 64];
  const int tid = threadIdx.x;
  const int r0 = blockIdx.x * 16;
#pragma unroll
  for (int i = 0; i < 32; ++i) {
    int idx = i * 256 + tid;
    W2f[(idx >> 7) * 129 + (idx & 127)] = we2[idx];
    W1f[(idx >> 6) * 65 + (idx & 63)] = wd1[idx];
  }
#pragma unroll
  for (int i = 0; i < 8; ++i) {
    int idx = i * 256 + tid;
    E1f[idx] = e1[(size_t)r0 * 128 + idx];
  }
  __syncthreads();
#pragma unroll
  for (int o = 0; o < 4; ++o) {
    int idx = o * 256 + tid;
    int r = idx >> 6, cc = idx & 63;
    float acc = 0.f;
#pragma unroll 8
    for (int c = 0; c < 128; ++c) acc += E1f[r * 128 + c] * W2f[cc * 129 + c];
    acc = fmaxf(acc, 0.f);
    ENf[r * 64 + cc] = acc;
    enc_out[(size_t)(r0 + r) * 64 + cc] = acc;
  }
  __syncthreads();
#pragma unroll
  for (int o = 0; o < 8; ++o) {
    int idx = o * 256 + tid;
    int r = idx >> 7, cc = idx & 127;
    float acc = 0.f;
#pragma unroll 8
    for (int c = 0; c < 64; ++c) acc += ENf[r * 64 + c] * W1f[cc * 65 + c];
    acc = fmaxf(acc, 0.f);
    u16 hi = f2bf(acc);
    d1h[(size_t)(r0 + r) * 128 + cc] = hi;
    d1l[(size_t)(r0 + r) * 128 + cc] = f2bf(acc - bf2f(hi));
  }
}

// ---------------- launch ----------------
extern "C" void kernel_launch(void* const* d_in, const int* in_sizes, int n_in,
                              void* d_out, int out_size, void* d_ws, size_t ws_size,
                              hipStream_t stream) {
  const float* x     = (const float*)d_in[0];
  const float* w_in  = (const float*)d_in[1];
  const float* w_out = (const float*)d_in[2];
  const float* w_e1  = (const float*)d_in[3];
  const float* w_e2  = (const float*)d_in[4];
  const float* w_d1  = (const float*)d_in[5];
  const float* w_d2  = (const float*)d_in[6];

  char* ws = (char*)d_ws;
  u16* qkvb  = (u16*)(ws + 0);           // 100,663,296  [until attn done]
  u16* hbh   = (u16*)(ws + 0);           // 33,554,432   [after attn]
  u16* hbl   = (u16*)(ws + 33554432);    // 33,554,432
  float* e1b = (float*)(ws + 67108864);  // 8,388,608 (fp32)
  u16* d1oh  = (u16*)(ws + 75497472);    // 4,194,304
  u16* d1ol  = (u16*)(ws + 79691776);    // 4,194,304
  float* Sb  = (float*)(ws + 100663296); // 33,554,432 (8 heads x 1024 x 1024 fp32)
  u16* xb    = (u16*)(ws + 134217728);   // 33,554,432   [until qkv gemm]
  u16* ctxb  = (u16*)(ws + 134217728);   // reuses xb
  u16* aob   = (u16*)(ws + 167772160);   // 33,554,432
  u16* wbin  = (u16*)(ws + 201326592);   // 6,291,456
  u16* wbout = (u16*)(ws + 207618048);   // 2,097,152
  u16* wbe1h = (u16*)(ws + 209715200);   // 262,144
  u16* wbe1l = (u16*)(ws + 209977344);   // 262,144
  u16* wbd2h = (u16*)(ws + 210239488);   // 262,144
  u16* wbd2l = (u16*)(ws + 210501632);   // 262,144

  float* recon = (float*)d_out;
  float* enc_out = (float*)d_out + 16777216;

  k_cvt<<<8192, 256, 0, stream>>>(x, xb, 16777216);
  k_cvt<<<1536, 256, 0, stream>>>(w_in, wbin, 3145728);
  k_cvt<<<512, 256, 0, stream>>>(w_out, wbout, 1048576);
  k_cvt2<<<64, 256, 0, stream>>>(w_e1, wbe1h, wbe1l, 131072);
  k_cvt2<<<64, 256, 0, stream>>>(w_d2, wbd2h, wbd2l, 131072);

  k_gemm<false, u16><<<dim3(24, 128), 256, 0, stream>>>(xb, wbin, qkvb, 16384, 3072, 1024);

  for (int b = 0; b < 16; ++b) {
    k_qkt<<<dim3(8, 8, 8), 256, 0, stream>>>(qkvb, Sb, b);
    k_softmax<<<dim3(1024, 8), 256, 0, stream>>>(Sb);
    k_pv8<<<dim3(128, 8), 128, 0, stream>>>(qkvb, Sb, ctxb, b);
  }

  k_gemm<false, u16><<<dim3(8, 128), 256, 0, stream>>>(ctxb, wbout, aob, 16384, 1024, 1024);
  k_ln2<<<16384, 256, 0, stream>>>(aob, x, hbh, hbl);
  k_gemm3<true><<<dim3(1, 128), 256, 0, stream>>>(hbh, hbl, wbe1h, wbe1l, e1b, 16384, 128, 1024);
  k_mid2<<<1024, 256, 0, stream>>>(e1b, w_e2, w_d1, enc_out, d1oh, d1ol);
  k_gemm3<false><<<dim3(8, 128), 256, 0, stream>>>(d1oh, d1ol, wbd2h, wbd2l, recon, 16384, 1024, 128);
}